// Round 14
// baseline (120.983 us; speedup 1.0000x reference)
//
#include <hip/hip_runtime.h>
#include <hip/hip_bf16.h>

// Problem constants
#define M_TOK 4928   // B*T = 64*77
#define M_PAD 5120   // Xb/Xq row allocation
#define M_GMM 4992   // 39*128 rows actually computed
#define D_DIM 768
#define NR    4096   // N*R = 1024*4

typedef __bf16 bf16;
typedef unsigned char u8;   // raw fp8 e4m3 byte
typedef __attribute__((ext_vector_type(8))) __bf16 bf16x8;
typedef __attribute__((ext_vector_type(4))) float f32x4;
typedef __attribute__((address_space(1))) uint32_t gu32;
typedef __attribute__((address_space(3))) uint32_t su32;

// ALWAYS offset=0 (R11: nonzero offset shifts the LDS destination -> NaN).
#define GLDS(P, LDSP) \
  __builtin_amdgcn_global_load_lds((gu32*)(P), (su32*)(LDSP), 16, 0, 0)

// pack 4 f32 -> 4 fp8 e4m3 (RNE, saturating) in one u32
__device__ __forceinline__ uint32_t pk_fp8x4(float a, float b, float c, float d) {
  uint32_t w = 0;
  w = (uint32_t)__builtin_amdgcn_cvt_pk_fp8_f32(a, b, (int)w, false);
  w = (uint32_t)__builtin_amdgcn_cvt_pk_fp8_f32(c, d, (int)w, true);
  return w;
}

// sigma-GELU: x * sigmoid(1.702 x); act error swamped by diag(~0.02) squashing.
__device__ __forceinline__ float act_fast(float v) {
  float e = __builtin_amdgcn_exp2f(v * -2.4554677f);
  return v * __builtin_amdgcn_rcpf(1.0f + e);
}

// m204 bijective XCD swizzle
__device__ __forceinline__ int xcd_swizzle(int orig, int nwg) {
  const int q = nwg >> 3, r = nwg & 7;
  const int x = orig & 7, rest = orig >> 3;
  return (x < r ? x * (q + 1) : r * (q + 1) + (x - r) * q) + rest;
}

// ---------------- prep kernels ----------------

__global__ __launch_bounds__(256) void k_prep_x(const float* __restrict__ x,
                                                bf16* __restrict__ Xb) {
  int idx = (blockIdx.x * 256 + threadIdx.x) * 4;
  if (idx >= M_PAD * D_DIM) return;
  int m = idx / D_DIM;
  union { uint2 u; bf16 h[4]; } o;
  if (m < M_TOK) {
    float4 v = *(const float4*)(x + idx);
    o.h[0] = (bf16)v.x; o.h[1] = (bf16)v.y; o.h[2] = (bf16)v.z; o.h[3] = (bf16)v.w;
  } else {
    o.h[0] = o.h[1] = o.h[2] = o.h[3] = (bf16)0.0f;
  }
  *(uint2*)(Xb + idx) = o.u;
}

// x fp32 -> Xq fp8 e4m3, pad rows zero.  X ~ N(0,1): no scale.
__global__ __launch_bounds__(256) void k_prep_xq(const float* __restrict__ x,
                                                 u8* __restrict__ Xq) {
  int idx = (blockIdx.x * 256 + threadIdx.x) * 4;
  if (idx >= M_PAD * D_DIM) return;
  int m = idx / D_DIM;
  uint32_t w = 0;
  if (m < M_TOK) {
    float4 v = *(const float4*)(x + idx);
    w = pk_fp8x4(v.x, v.y, v.z, v.w);
  }
  *(uint32_t*)(Xq + idx) = w;
}

// w1 fp32 [N][D][R] -> W1q fp8 [4096 j][768 d], scaled x64 (epilogue /64).
__global__ __launch_bounds__(256) void k_prep_w1q(const float* __restrict__ w1,
                                                  u8* __restrict__ W1q) {
  int gid = blockIdx.x * 256 + threadIdx.x;   // 98304
  int n = gid / 96, oct = gid % 96;
  const float4* src = (const float4*)w1 + (size_t)n * D_DIM + oct * 8;
  float e[4][8];
#pragma unroll
  for (int d = 0; d < 8; ++d) {
    float4 v = src[d];
    e[0][d] = v.x * 64.0f; e[1][d] = v.y * 64.0f;
    e[2][d] = v.z * 64.0f; e[3][d] = v.w * 64.0f;
  }
  size_t base = (size_t)n * 4 * D_DIM + oct * 8;
#pragma unroll
  for (int r = 0; r < 4; ++r) {
    uint2 o;
    o.x = pk_fp8x4(e[r][0], e[r][1], e[r][2], e[r][3]);
    o.y = pk_fp8x4(e[r][4], e[r][5], e[r][6], e[r][7]);
    *(uint2*)(W1q + base + (size_t)r * D_DIM) = o;
  }
}

// w_out fp32 [4096 k][768 d] -> W2q fp8 [768 d][4096 k] = 16*w_out (0.25*64)
__global__ __launch_bounds__(256) void k_prep_w2q(const float* __restrict__ w_out,
                                                  u8* __restrict__ W2q) {
  __shared__ float S[64 * 65];
  const int bk = blockIdx.x & 63, bd = blockIdx.x >> 6;  // 64 k-tiles x 12 d-tiles
  const int k0 = bk * 64, d0 = bd * 64;
  const int tr = threadIdx.x >> 4;        // 0..15
  const int tc = (threadIdx.x & 15) * 4;  // 0..60
#pragma unroll
  for (int p = 0; p < 4; ++p) {
    const int kr = tr + p * 16;
    float4 v = *(const float4*)(w_out + (size_t)(k0 + kr) * D_DIM + d0 + tc);
    S[kr * 65 + tc + 0] = v.x; S[kr * 65 + tc + 1] = v.y;
    S[kr * 65 + tc + 2] = v.z; S[kr * 65 + tc + 3] = v.w;
  }
  __syncthreads();
#pragma unroll
  for (int p = 0; p < 4; ++p) {
    const int dr = tr + p * 16;
    uint32_t w = pk_fp8x4(16.0f * S[(tc + 0) * 65 + dr], 16.0f * S[(tc + 1) * 65 + dr],
                          16.0f * S[(tc + 2) * 65 + dr], 16.0f * S[(tc + 3) * 65 + dr]);
    *(uint32_t*)(W2q + (size_t)(d0 + dr) * NR + k0 + tc) = w;
  }
}

// W_org fp32 [768][768] -> bf16 row-major copy
__global__ __launch_bounds__(256) void k_prep_worg(const float* __restrict__ W_org,
                                                   bf16* __restrict__ WorgB) {
  int idx = (blockIdx.x * 256 + threadIdx.x) * 4;
  if (idx >= D_DIM * D_DIM) return;
  float4 v = *(const float4*)(W_org + idx);
  union { uint2 u; bf16 h[4]; } o;
  o.h[0] = (bf16)v.x; o.h[1] = (bf16)v.y; o.h[2] = (bf16)v.z; o.h[3] = (bf16)v.w;
  *(uint2*)(WorgB + idx) = o.u;
}

__global__ __launch_bounds__(256) void k_bias_partial(const float* __restrict__ b_out,
                                                      float* __restrict__ partial) {
  int b = blockIdx.x;
  for (int d = threadIdx.x; d < D_DIM; d += 256) {
    float s = 0.0f;
    for (int n = b * 32; n < b * 32 + 32; ++n) s += b_out[n * D_DIM + d];
    partial[b * D_DIM + d] = s;
  }
}

// blocks 0-2: bias_total; blocks 3-18: diag[j] = mid_w[n][r][r]
__global__ __launch_bounds__(256) void k_bias_final2(const float* __restrict__ partial,
                                                     const float* __restrict__ b_org,
                                                     const float* __restrict__ mid_w,
                                                     float* __restrict__ bias_total,
                                                     float* __restrict__ diag) {
  int b = blockIdx.x;
  if (b < 3) {
    int d = b * 256 + threadIdx.x;
    if (d >= D_DIM) return;
    float s = 0.0f;
#pragma unroll
    for (int p = 0; p < 32; ++p) s += partial[p * D_DIM + d];
    bias_total[d] = b_org[d] + 0.25f * s;
  } else {
    int j = (b - 3) * 256 + threadIdx.x;
    diag[j] = mid_w[(j >> 2) * 16 + (j & 3) * 5];
  }
}

// ---------------- fp8 128x128/BK64 engine (R13-verified schedule) ----------
// 3 LDS slots of 128x64B; per iter: vmcnt(4) -> barrier -> 16x ds_read_b64
// (slot compile-time) -> stage tile kt+2 (4 GLDS, pointers += 64) -> 32 MFMA.

#define G1F_IT(S_, DO_STG, LAST_)                                               \
  {                                                                             \
    if (LAST_) { asm volatile("s_waitcnt vmcnt(0)" ::: "memory"); }             \
    else       { asm volatile("s_waitcnt vmcnt(4)" ::: "memory"); }             \
    asm volatile("s_barrier" ::: "memory");                                     \
    long a0[4], a1[4], b0[4], b1[4];                                            \
    _Pragma("unroll") for (int i = 0; i < 4; ++i) {                             \
      a0[i] = *(const long*)(&As[S_][aOff + i * 1024]);                         \
      a1[i] = *(const long*)(&As[S_][(aOff ^ 32) + i * 1024]);                  \
    }                                                                           \
    _Pragma("unroll") for (int j = 0; j < 4; ++j) {                             \
      b0[j] = *(const long*)(&Bs[S_][bOff + j * 1024]);                         \
      b1[j] = *(const long*)(&Bs[S_][(bOff ^ 32) + j * 1024]);                  \
    }                                                                           \
    if (DO_STG) {                                                               \
      GLDS(aP0, &As[((S_) + 2) % 3][ldsC0]);                                    \
      GLDS(aP1, &As[((S_) + 2) % 3][ldsC1]);                                    \
      GLDS(bP0, &Bs[((S_) + 2) % 3][ldsC0]);                                    \
      GLDS(bP1, &Bs[((S_) + 2) % 3][ldsC1]);                                    \
      aP0 += 64; aP1 += 64; bP0 += 64; bP1 += 64;                               \
    }                                                                           \
    _Pragma("unroll") for (int i = 0; i < 4; ++i)                               \
      _Pragma("unroll") for (int j = 0; j < 4; ++j)                             \
        acc[i][j] = __builtin_amdgcn_mfma_f32_16x16x32_fp8_fp8(b0[j], a0[i], acc[i][j], 0, 0, 0); \
    _Pragma("unroll") for (int i = 0; i < 4; ++i)                               \
      _Pragma("unroll") for (int j = 0; j < 4; ++j)                             \
        acc[i][j] = __builtin_amdgcn_mfma_f32_16x16x32_fp8_fp8(b1[j], a1[i], acc[i][j], 0, 0, 0); \
  }

// GEMM1: Xq[.,768]8 x W1q[4096,768]8 -> H2q fp8 [4992,4096] (x128 scale)
__global__ __launch_bounds__(256) void k_gemm1(const u8* __restrict__ Xq,
                                               const u8* __restrict__ W1q,
                                               u8* __restrict__ H2q,
                                               const float* __restrict__ b1,
                                               const float* __restrict__ diag,
                                               const float* __restrict__ midb) {
  __shared__ u8 As[3][128 * 64];
  __shared__ u8 Bs[3][128 * 64];
  const int wgid = xcd_swizzle(blockIdx.x, 39 * 32);
  const int bmt = wgid >> 5;
  const int bnt = wgid & 31;
  const int m0 = bmt * 128, n0 = bnt * 128;
  const int lane = threadIdx.x & 63;
  const int wave = threadIdx.x >> 6;
  const int wm = wave >> 1, wn = wave & 1;
  const int lr = lane & 15, kg = lane >> 4;
  const int slotB = (((kg >> 1) ^ ((lr >> 1) & 3)) << 4) + ((kg & 1) << 3);
  const int aOff = (wm * 64 + lr) * 64 + slotB;
  const int bOff = (wn * 64 + lr) * 64 + slotB;

  const int src_slot = (lane & 3) ^ ((lane >> 3) & 3);
  const int srow = (wave * 2) * 16 + (lane >> 2);
  const u8* aP0 = Xq  + (size_t)(m0 + srow) * D_DIM + (src_slot << 4);
  const u8* aP1 = aP0 + 16 * D_DIM;
  const u8* bP0 = W1q + (size_t)(n0 + srow) * D_DIM + (src_slot << 4);
  const u8* bP1 = bP0 + 16 * D_DIM;
  const int ldsC0 = (wave * 2) * 1024, ldsC1 = ldsC0 + 1024;

  f32x4 acc[4][4];
#pragma unroll
  for (int i = 0; i < 4; ++i)
#pragma unroll
    for (int j = 0; j < 4; ++j) acc[i][j] = (f32x4)(0.0f);

  GLDS(aP0, &As[0][ldsC0]); GLDS(aP1, &As[0][ldsC1]);
  GLDS(bP0, &Bs[0][ldsC0]); GLDS(bP1, &Bs[0][ldsC1]);
  aP0 += 64; aP1 += 64; bP0 += 64; bP1 += 64;
  GLDS(aP0, &As[1][ldsC0]); GLDS(aP1, &As[1][ldsC1]);
  GLDS(bP0, &Bs[1][ldsC0]); GLDS(bP1, &Bs[1][ldsC1]);
  aP0 += 64; aP1 += 64; bP0 += 64; bP1 += 64;

  for (int g = 0; g < 3; ++g) {
    G1F_IT(0, true, false)
    G1F_IT(1, true, false)
    G1F_IT(2, true, false)
  }
  G1F_IT(0, true, false)
  G1F_IT(1, false, false)
  G1F_IT(2, false, true)

  // epilogue: acc = 64*h1 -> x2^-6; h2 stored fp8 x128
#pragma unroll
  for (int j = 0; j < 4; ++j) {
    const int jcb = n0 + wn * 64 + j * 16 + kg * 4;
    const float4 b1v = *(const float4*)(b1 + jcb);
    const float4 dgv = *(const float4*)(diag + jcb);
    const float4 mbv = *(const float4*)(midb + jcb);
#pragma unroll
    for (int i = 0; i < 4; ++i) {
      const int mr = m0 + wm * 64 + i * 16 + lr;
      float h, f0, f1, f2, f3;
      h = act_fast(fmaf(acc[i][j][0], 0.015625f, b1v.x)); f0 = act_fast(h * dgv.x + mbv.x);
      h = act_fast(fmaf(acc[i][j][1], 0.015625f, b1v.y)); f1 = act_fast(h * dgv.y + mbv.y);
      h = act_fast(fmaf(acc[i][j][2], 0.015625f, b1v.z)); f2 = act_fast(h * dgv.z + mbv.z);
      h = act_fast(fmaf(acc[i][j][3], 0.015625f, b1v.w)); f3 = act_fast(h * dgv.w + mbv.w);
      uint32_t w = pk_fp8x4(f0 * 128.0f, f1 * 128.0f, f2 * 128.0f, f3 * 128.0f);
      *(uint32_t*)(H2q + (size_t)mr * NR + jcb) = w;
    }
  }
}

// GEMM2a (up-path): H2q[4992,4096]8 x W2q[768,4096]8 -> bf16 partials[4].
// Same engine; split-K=4 (1024 each = 16 BK64 tiles). acc scale 1/(128*16).
__global__ __launch_bounds__(256) void k_gemm2a(const u8* __restrict__ H2q,
                                                const u8* __restrict__ W2q,
                                                bf16* __restrict__ padd) {
  __shared__ u8 As[3][128 * 64];
  __shared__ u8 Bs[3][128 * 64];
  const int wgid = xcd_swizzle(blockIdx.x, 39 * 6 * 4);
  const int bmt = wgid / 24;
  const int rem = wgid % 24;
  const int ks  = rem / 6;
  const int bnt = rem % 6;               // 6 consecutive share A-panel
  const int m0 = bmt * 128, n0 = bnt * 128;
  const int kbase = ks * 1024;           // K elements (== bytes, fp8)
  const int lane = threadIdx.x & 63;
  const int wave = threadIdx.x >> 6;
  const int wm = wave >> 1, wn = wave & 1;
  const int lr = lane & 15, kg = lane >> 4;
  const int slotB = (((kg >> 1) ^ ((lr >> 1) & 3)) << 4) + ((kg & 1) << 3);
  const int aOff = (wm * 64 + lr) * 64 + slotB;
  const int bOff = (wn * 64 + lr) * 64 + slotB;

  const int src_slot = (lane & 3) ^ ((lane >> 3) & 3);
  const int srow = (wave * 2) * 16 + (lane >> 2);
  const u8* aP0 = H2q + (size_t)(m0 + srow) * NR + kbase + (src_slot << 4);
  const u8* aP1 = aP0 + 16 * NR;
  const u8* bP0 = W2q + (size_t)(n0 + srow) * NR + kbase + (src_slot << 4);
  const u8* bP1 = bP0 + 16 * NR;
  const int ldsC0 = (wave * 2) * 1024, ldsC1 = ldsC0 + 1024;

  f32x4 acc[4][4];
#pragma unroll
  for (int i = 0; i < 4; ++i)
#pragma unroll
    for (int j = 0; j < 4; ++j) acc[i][j] = (f32x4)(0.0f);

  GLDS(aP0, &As[0][ldsC0]); GLDS(aP1, &As[0][ldsC1]);
  GLDS(bP0, &Bs[0][ldsC0]); GLDS(bP1, &Bs[0][ldsC1]);
  aP0 += 64; aP1 += 64; bP0 += 64; bP1 += 64;
  GLDS(aP0, &As[1][ldsC0]); GLDS(aP1, &As[1][ldsC1]);
  GLDS(bP0, &Bs[1][ldsC0]); GLDS(bP1, &Bs[1][ldsC1]);
  aP0 += 64; aP1 += 64; bP0 += 64; bP1 += 64;

  // 16 iters: kt0-11 (4 groups), kt12-13 stage tail, kt14-15 drain
  for (int g = 0; g < 4; ++g) {
    G1F_IT(0, true, false)
    G1F_IT(1, true, false)
    G1F_IT(2, true, false)
  }
  G1F_IT(0, true, false)   // kt12 stages t14
  G1F_IT(1, true, false)   // kt13 stages t15
  G1F_IT(2, false, false)  // kt14
  G1F_IT(0, false, true)   // kt15

  bf16* dst = padd + (size_t)ks * M_TOK * D_DIM;
#pragma unroll
  for (int j = 0; j < 4; ++j) {
    const int cb = n0 + wn * 64 + j * 16 + kg * 4;
#pragma unroll
    for (int i = 0; i < 4; ++i) {
      const int mr = m0 + wm * 64 + i * 16 + lr;
      if (mr < M_TOK) {
        union { uint2 u; bf16 h[4]; } o;
        o.h[0] = (bf16)(acc[i][j][0] * 4.8828125e-4f);
        o.h[1] = (bf16)(acc[i][j][1] * 4.8828125e-4f);
        o.h[2] = (bf16)(acc[i][j][2] * 4.8828125e-4f);
        o.h[3] = (bf16)(acc[i][j][3] * 4.8828125e-4f);
        *(uint2*)(dst + (size_t)mr * D_DIM + cb) = o.u;
      }
    }
  }
}

// ---------------- bf16 128x128/BK32 engine (R12-verified) for org path ------

#define G1B_IT(S_, DO_STG, LAST_)                                               \
  {                                                                             \
    if (LAST_) { asm volatile("s_waitcnt vmcnt(0)" ::: "memory"); }             \
    else       { asm volatile("s_waitcnt vmcnt(4)" ::: "memory"); }             \
    asm volatile("s_barrier" ::: "memory");                                     \
    bf16x8 a_[4], b_[4];                                                        \
    _Pragma("unroll") for (int i = 0; i < 4; ++i)                               \
      a_[i] = *(const bf16x8*)(&As[S_][aOff + i * 512]);                        \
    _Pragma("unroll") for (int j = 0; j < 4; ++j)                               \
      b_[j] = *(const bf16x8*)(&Bs[S_][bOff + j * 512]);                        \
    if (DO_STG) {                                                               \
      GLDS(aP0, &As[((S_) + 2) % 3][ldsC0]);                                    \
      GLDS(aP1, &As[((S_) + 2) % 3][ldsC1]);                                    \
      GLDS(bP0, &Bs[((S_) + 2) % 3][ldsC0]);                                    \
      GLDS(bP1, &Bs[((S_) + 2) % 3][ldsC1]);                                    \
      aP0 += 32; aP1 += 32; bP0 += 32; bP1 += 32;                               \
    }                                                                           \
    _Pragma("unroll") for (int i = 0; i < 4; ++i)                               \
      _Pragma("unroll") for (int j = 0; j < 4; ++j)                             \
        acc[i][j] = __builtin_amdgcn_mfma_f32_16x16x32_bf16(b_[j], a_[i], acc[i][j], 0, 0, 0); \
  }

// GEMM2b (org): Xb[.,768] x WorgB[768,768] -> out fp32 + bias (written FIRST,
// reduce then accumulates the up-path partials onto it)
__global__ __launch_bounds__(256) void k_gemm2b(const bf16* __restrict__ Xb,
                                                const bf16* __restrict__ WorgB,
                                                float* __restrict__ out,
                                                const float* __restrict__ bias) {
  __shared__ bf16 As[3][128 * 32];
  __shared__ bf16 Bs[3][128 * 32];
  const int wgid = xcd_swizzle(blockIdx.x, 39 * 6);
  const int bmt = wgid / 6;
  const int bnt = wgid % 6;
  const int m0 = bmt * 128, n0 = bnt * 128;
  const int lane = threadIdx.x & 63;
  const int wave = threadIdx.x >> 6;
  const int wm = wave >> 1, wn = wave & 1;
  const int lr = lane & 15, kg = lane >> 4;
  const int slot = (kg ^ ((lr >> 1) & 3)) << 3;
  const int aOff = (wm * 64 + lr) * 32 + slot;
  const int bOff = (wn * 64 + lr) * 32 + slot;

  const int src_slot = (lane & 3) ^ ((lane >> 3) & 3);
  const int srow = (wave * 2) * 16 + (lane >> 2);
  const bf16* aP0 = Xb    + (size_t)(m0 + srow) * D_DIM + (src_slot << 3);
  const bf16* aP1 = aP0 + 16 * D_DIM;
  const bf16* bP0 = WorgB + (size_t)(n0 + srow) * D_DIM + (src_slot << 3);
  const bf16* bP1 = bP0 + 16 * D_DIM;
  const int ldsC0 = (wave * 2) * 512, ldsC1 = ldsC0 + 512;

  f32x4 acc[4][4];
#pragma unroll
  for (int i = 0; i < 4; ++i)
#pragma unroll
    for (int j = 0; j < 4; ++j) acc[i][j] = (f32x4)(0.0f);

  GLDS(aP0, &As[0][ldsC0]); GLDS(aP1, &As[0][ldsC1]);
  GLDS(bP0, &Bs[0][ldsC0]); GLDS(bP1, &Bs[0][ldsC1]);
  aP0 += 32; aP1 += 32; bP0 += 32; bP1 += 32;
  GLDS(aP0, &As[1][ldsC0]); GLDS(aP1, &As[1][ldsC1]);
  GLDS(bP0, &Bs[1][ldsC0]); GLDS(bP1, &Bs[1][ldsC1]);
  aP0 += 32; aP1 += 32; bP0 += 32; bP1 += 32;

  for (int g = 0; g < 7; ++g) {
    G1B_IT(0, true, false)
    G1B_IT(1, true, false)
    G1B_IT(2, true, false)
  }
  G1B_IT(0, true, false)
  G1B_IT(1, false, false)
  G1B_IT(2, false, true)

#pragma unroll
  for (int j = 0; j < 4; ++j) {
    const int cb = n0 + wn * 64 + j * 16 + kg * 4;
    const f32x4 bv = *(const f32x4*)(bias + cb);
#pragma unroll
    for (int i = 0; i < 4; ++i) {
      const int mr = m0 + wm * 64 + i * 16 + lr;
      if (mr < M_TOK) {
        f32x4 o = acc[i][j] + bv;
        *(f32x4*)(out + (size_t)mr * D_DIM + cb) = o;
      }
    }
  }
}

// out += sum of 4 bf16 up-path partials (org + bias already in out)
__global__ __launch_bounds__(256) void k_reduce(const bf16* __restrict__ padd,
                                                float* __restrict__ out) {
  int idx = (blockIdx.x * 256 + threadIdx.x) * 4;
  if (idx >= M_TOK * D_DIM) return;
  float4 s = *(const float4*)(out + idx);
#pragma unroll
  for (int p = 0; p < 4; ++p) {
    union { uint2 u; bf16 h[4]; } v;
    v.u = *(const uint2*)(padd + (size_t)p * M_TOK * D_DIM + idx);
    s.x += (float)v.h[0]; s.y += (float)v.h[1];
    s.z += (float)v.h[2]; s.w += (float)v.h[3];
  }
  *(float4*)(out + idx) = s;
}

// ---------------- launch ----------------

extern "C" void kernel_launch(void* const* d_in, const int* in_sizes, int n_in,
                              void* d_out, int out_size, void* d_ws, size_t ws_size,
                              hipStream_t stream) {
  const float* x     = (const float*)d_in[0];
  const float* W_org = (const float*)d_in[1];
  const float* b_org = (const float*)d_in[2];
  const float* w1    = (const float*)d_in[3];
  const float* b1    = (const float*)d_in[4];
  const float* mid_w = (const float*)d_in[5];
  const float* mid_b = (const float*)d_in[6];
  const float* w_out = (const float*)d_in[7];
  const float* b_out = (const float*)d_in[8];
  float* out = (float*)d_out;

  // workspace carve-up (~67 MB, smaller than R13's)
  bf16* Xb    = (bf16*)d_ws;                        // 5120*768
  bf16* WorgB = Xb + (size_t)M_PAD * D_DIM;         // 768*768
  float* bias    = (float*)(WorgB + (size_t)D_DIM * D_DIM);
  float* partial = bias + 1024;                     // 32*768
  float* diag    = partial + 32 * D_DIM;            // 4096
  u8* Xq   = (u8*)(diag + NR);                      // 5120*768
  u8* W1q  = Xq  + (size_t)M_PAD * D_DIM;           // 4096*768
  u8* W2q  = W1q + (size_t)NR * D_DIM;              // 768*4096
  u8* H2q  = W2q + (size_t)D_DIM * NR;              // 4992*4096
  bf16* padd = (bf16*)(H2q + (size_t)M_GMM * NR);   // 4 * 4928*768

  k_prep_x      <<<(M_PAD * D_DIM / 4) / 256, 256, 0, stream>>>(x, Xb);
  k_prep_xq     <<<(M_PAD * D_DIM / 4) / 256, 256, 0, stream>>>(x, Xq);
  k_prep_w1q    <<<384, 256, 0, stream>>>(w1, W1q);
  k_prep_w2q    <<<64 * 12, 256, 0, stream>>>(w_out, W2q);
  k_prep_worg   <<<(D_DIM * D_DIM / 4 + 255) / 256, 256, 0, stream>>>(W_org, WorgB);
  k_bias_partial<<<32, 256, 0, stream>>>(b_out, partial);
  k_bias_final2 <<<19, 256, 0, stream>>>(partial, b_org, mid_w, bias, diag);

  k_gemm1 <<<39 * 32, 256, 0, stream>>>(Xq, W1q, H2q, b1, diag, mid_b);
  k_gemm2a<<<39 * 6 * 4, 256, 0, stream>>>(H2q, W2q, padd);
  k_gemm2b<<<39 * 6, 256, 0, stream>>>(Xb, WorgB, out, bias);

  k_reduce<<<(M_TOK * D_DIM / 4) / 256, 256, 0, stream>>>(padd, out);
}

// Round 15
// 118.733 us; speedup vs baseline: 1.0189x; 1.0189x over previous
//
#include <hip/hip_runtime.h>
#include <hip/hip_bf16.h>

// Problem constants
#define M_TOK 4928   // B*T = 64*77
#define M_PAD 5120   // Xb/Xq row allocation
#define M_GMM 4992   // 39*128 rows actually computed
#define D_DIM 768
#define NR    4096   // N*R = 1024*4

typedef __bf16 bf16;
typedef unsigned char u8;   // raw fp8 e4m3 byte
typedef __attribute__((ext_vector_type(8))) __bf16 bf16x8;
typedef __attribute__((ext_vector_type(4))) float f32x4;
typedef __attribute__((ext_vector_type(2))) long longx2;
typedef __attribute__((address_space(1))) uint32_t gu32;
typedef __attribute__((address_space(3))) uint32_t su32;

// ALWAYS offset=0 (R11: nonzero offset shifts the LDS destination -> NaN).
#define GLDS(P, LDSP) \
  __builtin_amdgcn_global_load_lds((gu32*)(P), (su32*)(LDSP), 16, 0, 0)

// k-interleave within each 64-byte K-group: storage p = (k&7) + ((k>>5)&1)*8
// + ((k>>3)&3)*16.  Makes storage-slot kg (16B) hold k {kg*8..+7, 32+kg*8..+7}
// = one lane's BOTH fp8 k-slices -> single conflict-free ds_read_b128
// (R12-verified geometry) instead of two 4-way-conflicting ds_read_b64 (R14:
// 3.83M conflict cycles).
__device__ __forceinline__ int ilv4(int k) {   // k 4-byte aligned
  return (k & ~63) + (k & 4) + (((k >> 5) & 1) << 3) + (((k >> 3) & 3) << 4);
}
__device__ __forceinline__ int ilv8(int k) {   // k 8-byte aligned
  return (k & ~63) + (((k >> 5) & 1) << 3) + (((k >> 3) & 3) << 4);
}

// pack 4 f32 -> 4 fp8 e4m3 (RNE, saturating) in one u32
__device__ __forceinline__ uint32_t pk_fp8x4(float a, float b, float c, float d) {
  uint32_t w = 0;
  w = (uint32_t)__builtin_amdgcn_cvt_pk_fp8_f32(a, b, (int)w, false);
  w = (uint32_t)__builtin_amdgcn_cvt_pk_fp8_f32(c, d, (int)w, true);
  return w;
}

// sigma-GELU: x * sigmoid(1.702 x); act error swamped by diag(~0.02) squashing.
__device__ __forceinline__ float act_fast(float v) {
  float e = __builtin_amdgcn_exp2f(v * -2.4554677f);
  return v * __builtin_amdgcn_rcpf(1.0f + e);
}

// m204 bijective XCD swizzle
__device__ __forceinline__ int xcd_swizzle(int orig, int nwg) {
  const int q = nwg >> 3, r = nwg & 7;
  const int x = orig & 7, rest = orig >> 3;
  return (x < r ? x * (q + 1) : r * (q + 1) + (x - r) * q) + rest;
}

// ---------------- prep kernels ----------------

__global__ __launch_bounds__(256) void k_prep_x(const float* __restrict__ x,
                                                bf16* __restrict__ Xb) {
  int idx = (blockIdx.x * 256 + threadIdx.x) * 4;
  if (idx >= M_PAD * D_DIM) return;
  int m = idx / D_DIM;
  union { uint2 u; bf16 h[4]; } o;
  if (m < M_TOK) {
    float4 v = *(const float4*)(x + idx);
    o.h[0] = (bf16)v.x; o.h[1] = (bf16)v.y; o.h[2] = (bf16)v.z; o.h[3] = (bf16)v.w;
  } else {
    o.h[0] = o.h[1] = o.h[2] = o.h[3] = (bf16)0.0f;
  }
  *(uint2*)(Xb + idx) = o.u;
}

// x fp32 -> Xq fp8 e4m3 (k-interleaved), pad rows zero.
__global__ __launch_bounds__(256) void k_prep_xq(const float* __restrict__ x,
                                                 u8* __restrict__ Xq) {
  int idx = (blockIdx.x * 256 + threadIdx.x) * 4;
  if (idx >= M_PAD * D_DIM) return;
  int m = idx / D_DIM, c = idx % D_DIM;
  uint32_t w = 0;
  if (m < M_TOK) {
    float4 v = *(const float4*)(x + idx);
    w = pk_fp8x4(v.x, v.y, v.z, v.w);
  }
  *(uint32_t*)(Xq + (size_t)m * D_DIM + ilv4(c)) = w;
}

// w1 fp32 [N][D][R] -> W1q fp8 [4096 j][768 d] (k-interleaved), scaled x64.
__global__ __launch_bounds__(256) void k_prep_w1q(const float* __restrict__ w1,
                                                  u8* __restrict__ W1q) {
  int gid = blockIdx.x * 256 + threadIdx.x;   // 98304
  int n = gid / 96, oct = gid % 96;
  const float4* src = (const float4*)w1 + (size_t)n * D_DIM + oct * 8;
  float e[4][8];
#pragma unroll
  for (int d = 0; d < 8; ++d) {
    float4 v = src[d];
    e[0][d] = v.x * 64.0f; e[1][d] = v.y * 64.0f;
    e[2][d] = v.z * 64.0f; e[3][d] = v.w * 64.0f;
  }
  const int cofs = ilv8(oct * 8);
#pragma unroll
  for (int r = 0; r < 4; ++r) {
    uint2 o;
    o.x = pk_fp8x4(e[r][0], e[r][1], e[r][2], e[r][3]);
    o.y = pk_fp8x4(e[r][4], e[r][5], e[r][6], e[r][7]);
    *(uint2*)(W1q + (size_t)(n * 4 + r) * D_DIM + cofs) = o;
  }
}

// w_out fp32 [4096 k][768 d] -> W2q fp8 [768 d][4096 k] = 16*w_out, interleaved
__global__ __launch_bounds__(256) void k_prep_w2q(const float* __restrict__ w_out,
                                                  u8* __restrict__ W2q) {
  __shared__ float S[64 * 65];
  const int bk = blockIdx.x & 63, bd = blockIdx.x >> 6;  // 64 k-tiles x 12 d-tiles
  const int k0 = bk * 64, d0 = bd * 64;
  const int tr = threadIdx.x >> 4;        // 0..15
  const int tc = (threadIdx.x & 15) * 4;  // 0..60
#pragma unroll
  for (int p = 0; p < 4; ++p) {
    const int kr = tr + p * 16;
    float4 v = *(const float4*)(w_out + (size_t)(k0 + kr) * D_DIM + d0 + tc);
    S[kr * 65 + tc + 0] = v.x; S[kr * 65 + tc + 1] = v.y;
    S[kr * 65 + tc + 2] = v.z; S[kr * 65 + tc + 3] = v.w;
  }
  __syncthreads();
#pragma unroll
  for (int p = 0; p < 4; ++p) {
    const int dr = tr + p * 16;
    uint32_t w = pk_fp8x4(16.0f * S[(tc + 0) * 65 + dr], 16.0f * S[(tc + 1) * 65 + dr],
                          16.0f * S[(tc + 2) * 65 + dr], 16.0f * S[(tc + 3) * 65 + dr]);
    *(uint32_t*)(W2q + (size_t)(d0 + dr) * NR + k0 + ilv4(tc)) = w;
  }
}

// W_org fp32 [768][768] -> bf16 row-major copy
__global__ __launch_bounds__(256) void k_prep_worg(const float* __restrict__ W_org,
                                                   bf16* __restrict__ WorgB) {
  int idx = (blockIdx.x * 256 + threadIdx.x) * 4;
  if (idx >= D_DIM * D_DIM) return;
  float4 v = *(const float4*)(W_org + idx);
  union { uint2 u; bf16 h[4]; } o;
  o.h[0] = (bf16)v.x; o.h[1] = (bf16)v.y; o.h[2] = (bf16)v.z; o.h[3] = (bf16)v.w;
  *(uint2*)(WorgB + idx) = o.u;
}

__global__ __launch_bounds__(256) void k_bias_partial(const float* __restrict__ b_out,
                                                      float* __restrict__ partial) {
  int b = blockIdx.x;
  for (int d = threadIdx.x; d < D_DIM; d += 256) {
    float s = 0.0f;
    for (int n = b * 32; n < b * 32 + 32; ++n) s += b_out[n * D_DIM + d];
    partial[b * D_DIM + d] = s;
  }
}

// blocks 0-2: bias_total; blocks 3-18: diag[j] = mid_w[n][r][r]
__global__ __launch_bounds__(256) void k_bias_final2(const float* __restrict__ partial,
                                                     const float* __restrict__ b_org,
                                                     const float* __restrict__ mid_w,
                                                     float* __restrict__ bias_total,
                                                     float* __restrict__ diag) {
  int b = blockIdx.x;
  if (b < 3) {
    int d = b * 256 + threadIdx.x;
    if (d >= D_DIM) return;
    float s = 0.0f;
#pragma unroll
    for (int p = 0; p < 32; ++p) s += partial[p * D_DIM + d];
    bias_total[d] = b_org[d] + 0.25f * s;
  } else {
    int j = (b - 3) * 256 + threadIdx.x;
    diag[j] = mid_w[(j >> 2) * 16 + (j & 3) * 5];
  }
}

// ---------------- fp8 128x128/BK64 engine (R13/R14 schedule, b128 reads) ----
// 3 LDS slots of 128x64B; per iter: vmcnt(4) -> barrier -> 8x ds_read_b128
// (conflict-free: 16B storage-slot = both k-slices, k-interleaved global) ->
// stage tile kt+2 (4 GLDS, pointers += 64) -> 32 MFMA.

#define G1F_IT(S_, DO_STG, LAST_)                                               \
  {                                                                             \
    if (LAST_) { asm volatile("s_waitcnt vmcnt(0)" ::: "memory"); }             \
    else       { asm volatile("s_waitcnt vmcnt(4)" ::: "memory"); }             \
    asm volatile("s_barrier" ::: "memory");                                     \
    longx2 av[4], bv[4];                                                        \
    _Pragma("unroll") for (int i = 0; i < 4; ++i)                               \
      av[i] = *(const longx2*)(&As[S_][aOff + i * 1024]);                       \
    _Pragma("unroll") for (int j = 0; j < 4; ++j)                               \
      bv[j] = *(const longx2*)(&Bs[S_][bOff + j * 1024]);                       \
    if (DO_STG) {                                                               \
      GLDS(aP0, &As[((S_) + 2) % 3][ldsC0]);                                    \
      GLDS(aP1, &As[((S_) + 2) % 3][ldsC1]);                                    \
      GLDS(bP0, &Bs[((S_) + 2) % 3][ldsC0]);                                    \
      GLDS(bP1, &Bs[((S_) + 2) % 3][ldsC1]);                                    \
      aP0 += 64; aP1 += 64; bP0 += 64; bP1 += 64;                               \
    }                                                                           \
    _Pragma("unroll") for (int i = 0; i < 4; ++i)                               \
      _Pragma("unroll") for (int j = 0; j < 4; ++j)                             \
        acc[i][j] = __builtin_amdgcn_mfma_f32_16x16x32_fp8_fp8(bv[j][0], av[i][0], acc[i][j], 0, 0, 0); \
    _Pragma("unroll") for (int i = 0; i < 4; ++i)                               \
      _Pragma("unroll") for (int j = 0; j < 4; ++j)                             \
        acc[i][j] = __builtin_amdgcn_mfma_f32_16x16x32_fp8_fp8(bv[j][1], av[i][1], acc[i][j], 0, 0, 0); \
  }

// GEMM1: Xq[.,768]8 x W1q[4096,768]8 -> H2q fp8 [4992,4096] (x128, interleaved)
__global__ __launch_bounds__(256) void k_gemm1(const u8* __restrict__ Xq,
                                               const u8* __restrict__ W1q,
                                               u8* __restrict__ H2q,
                                               const float* __restrict__ b1,
                                               const float* __restrict__ diag,
                                               const float* __restrict__ midb) {
  __shared__ u8 As[3][128 * 64];
  __shared__ u8 Bs[3][128 * 64];
  const int wgid = xcd_swizzle(blockIdx.x, 39 * 32);
  const int bmt = wgid >> 5;
  const int bnt = wgid & 31;
  const int m0 = bmt * 128, n0 = bnt * 128;
  const int lane = threadIdx.x & 63;
  const int wave = threadIdx.x >> 6;
  const int wm = wave >> 1, wn = wave & 1;
  const int lr = lane & 15, kg = lane >> 4;
  // b128 read: 16B storage-slot kg (XOR-swizzled like the verified bf16 path)
  const int slotB = (kg ^ ((lr >> 1) & 3)) << 4;
  const int aOff = (wm * 64 + lr) * 64 + slotB;
  const int bOff = (wn * 64 + lr) * 64 + slotB;

  const int src_slot = (lane & 3) ^ ((lane >> 3) & 3);
  const int srow = (wave * 2) * 16 + (lane >> 2);
  const u8* aP0 = Xq  + (size_t)(m0 + srow) * D_DIM + (src_slot << 4);
  const u8* aP1 = aP0 + 16 * D_DIM;
  const u8* bP0 = W1q + (size_t)(n0 + srow) * D_DIM + (src_slot << 4);
  const u8* bP1 = bP0 + 16 * D_DIM;
  const int ldsC0 = (wave * 2) * 1024, ldsC1 = ldsC0 + 1024;

  f32x4 acc[4][4];
#pragma unroll
  for (int i = 0; i < 4; ++i)
#pragma unroll
    for (int j = 0; j < 4; ++j) acc[i][j] = (f32x4)(0.0f);

  GLDS(aP0, &As[0][ldsC0]); GLDS(aP1, &As[0][ldsC1]);
  GLDS(bP0, &Bs[0][ldsC0]); GLDS(bP1, &Bs[0][ldsC1]);
  aP0 += 64; aP1 += 64; bP0 += 64; bP1 += 64;
  GLDS(aP0, &As[1][ldsC0]); GLDS(aP1, &As[1][ldsC1]);
  GLDS(bP0, &Bs[1][ldsC0]); GLDS(bP1, &Bs[1][ldsC1]);
  aP0 += 64; aP1 += 64; bP0 += 64; bP1 += 64;

  for (int g = 0; g < 3; ++g) {
    G1F_IT(0, true, false)
    G1F_IT(1, true, false)
    G1F_IT(2, true, false)
  }
  G1F_IT(0, true, false)
  G1F_IT(1, false, false)
  G1F_IT(2, false, true)

  // epilogue: acc = 64*h1 -> x2^-6; h2 stored fp8 x128, k-interleaved position
#pragma unroll
  for (int j = 0; j < 4; ++j) {
    const int jcb = n0 + wn * 64 + j * 16 + kg * 4;
    const float4 b1v = *(const float4*)(b1 + jcb);
    const float4 dgv = *(const float4*)(diag + jcb);
    const float4 mbv = *(const float4*)(midb + jcb);
    const int jq = j * 16 + kg * 4;
    const int pl = (jq & 4) + (((jq >> 5) & 1) << 3) + (((jq >> 3) & 3) << 4);
#pragma unroll
    for (int i = 0; i < 4; ++i) {
      const int mr = m0 + wm * 64 + i * 16 + lr;
      float h, f0, f1, f2, f3;
      h = act_fast(fmaf(acc[i][j][0], 0.015625f, b1v.x)); f0 = act_fast(h * dgv.x + mbv.x);
      h = act_fast(fmaf(acc[i][j][1], 0.015625f, b1v.y)); f1 = act_fast(h * dgv.y + mbv.y);
      h = act_fast(fmaf(acc[i][j][2], 0.015625f, b1v.z)); f2 = act_fast(h * dgv.z + mbv.z);
      h = act_fast(fmaf(acc[i][j][3], 0.015625f, b1v.w)); f3 = act_fast(h * dgv.w + mbv.w);
      uint32_t w = pk_fp8x4(f0 * 128.0f, f1 * 128.0f, f2 * 128.0f, f3 * 128.0f);
      *(uint32_t*)(H2q + (size_t)mr * NR + (n0 + wn * 64) + pl) = w;
    }
  }
}

// GEMM2a (up-path): H2q[4992,4096]8 x W2q[768,4096]8 -> bf16 partials[4].
__global__ __launch_bounds__(256) void k_gemm2a(const u8* __restrict__ H2q,
                                                const u8* __restrict__ W2q,
                                                bf16* __restrict__ padd) {
  __shared__ u8 As[3][128 * 64];
  __shared__ u8 Bs[3][128 * 64];
  const int wgid = xcd_swizzle(blockIdx.x, 39 * 6 * 4);
  const int bmt = wgid / 24;
  const int rem = wgid % 24;
  const int ks  = rem / 6;
  const int bnt = rem % 6;               // 6 consecutive share A-panel
  const int m0 = bmt * 128, n0 = bnt * 128;
  const int kbase = ks * 1024;           // K bytes (64-aligned: interleave intact)
  const int lane = threadIdx.x & 63;
  const int wave = threadIdx.x >> 6;
  const int wm = wave >> 1, wn = wave & 1;
  const int lr = lane & 15, kg = lane >> 4;
  const int slotB = (kg ^ ((lr >> 1) & 3)) << 4;
  const int aOff = (wm * 64 + lr) * 64 + slotB;
  const int bOff = (wn * 64 + lr) * 64 + slotB;

  const int src_slot = (lane & 3) ^ ((lane >> 3) & 3);
  const int srow = (wave * 2) * 16 + (lane >> 2);
  const u8* aP0 = H2q + (size_t)(m0 + srow) * NR + kbase + (src_slot << 4);
  const u8* aP1 = aP0 + 16 * NR;
  const u8* bP0 = W2q + (size_t)(n0 + srow) * NR + kbase + (src_slot << 4);
  const u8* bP1 = bP0 + 16 * NR;
  const int ldsC0 = (wave * 2) * 1024, ldsC1 = ldsC0 + 1024;

  f32x4 acc[4][4];
#pragma unroll
  for (int i = 0; i < 4; ++i)
#pragma unroll
    for (int j = 0; j < 4; ++j) acc[i][j] = (f32x4)(0.0f);

  GLDS(aP0, &As[0][ldsC0]); GLDS(aP1, &As[0][ldsC1]);
  GLDS(bP0, &Bs[0][ldsC0]); GLDS(bP1, &Bs[0][ldsC1]);
  aP0 += 64; aP1 += 64; bP0 += 64; bP1 += 64;
  GLDS(aP0, &As[1][ldsC0]); GLDS(aP1, &As[1][ldsC1]);
  GLDS(bP0, &Bs[1][ldsC0]); GLDS(bP1, &Bs[1][ldsC1]);
  aP0 += 64; aP1 += 64; bP0 += 64; bP1 += 64;

  // 16 iters: kt0-11 (4 groups), kt12-13 stage tail, kt14-15 drain
  for (int g = 0; g < 4; ++g) {
    G1F_IT(0, true, false)
    G1F_IT(1, true, false)
    G1F_IT(2, true, false)
  }
  G1F_IT(0, true, false)   // kt12 stages t14
  G1F_IT(1, true, false)   // kt13 stages t15
  G1F_IT(2, false, false)  // kt14
  G1F_IT(0, false, true)   // kt15

  bf16* dst = padd + (size_t)ks * M_TOK * D_DIM;
#pragma unroll
  for (int j = 0; j < 4; ++j) {
    const int cb = n0 + wn * 64 + j * 16 + kg * 4;
#pragma unroll
    for (int i = 0; i < 4; ++i) {
      const int mr = m0 + wm * 64 + i * 16 + lr;
      if (mr < M_TOK) {
        union { uint2 u; bf16 h[4]; } o;
        o.h[0] = (bf16)(acc[i][j][0] * 4.8828125e-4f);
        o.h[1] = (bf16)(acc[i][j][1] * 4.8828125e-4f);
        o.h[2] = (bf16)(acc[i][j][2] * 4.8828125e-4f);
        o.h[3] = (bf16)(acc[i][j][3] * 4.8828125e-4f);
        *(uint2*)(dst + (size_t)mr * D_DIM + cb) = o.u;
      }
    }
  }
}

// ---------------- bf16 128x128/BK32 engine (R12-verified) for org path ------

#define G1B_IT(S_, DO_STG, LAST_)                                               \
  {                                                                             \
    if (LAST_) { asm volatile("s_waitcnt vmcnt(0)" ::: "memory"); }             \
    else       { asm volatile("s_waitcnt vmcnt(4)" ::: "memory"); }             \
    asm volatile("s_barrier" ::: "memory");                                     \
    bf16x8 a_[4], b_[4];                                                        \
    _Pragma("unroll") for (int i = 0; i < 4; ++i)                               \
      a_[i] = *(const bf16x8*)(&As[S_][aOff + i * 512]);                        \
    _Pragma("unroll") for (int j = 0; j < 4; ++j)                               \
      b_[j] = *(const bf16x8*)(&Bs[S_][bOff + j * 512]);                        \
    if (DO_STG) {                                                               \
      GLDS(aP0, &As[((S_) + 2) % 3][ldsC0]);                                    \
      GLDS(aP1, &As[((S_) + 2) % 3][ldsC1]);                                    \
      GLDS(bP0, &Bs[((S_) + 2) % 3][ldsC0]);                                    \
      GLDS(bP1, &Bs[((S_) + 2) % 3][ldsC1]);                                    \
      aP0 += 32; aP1 += 32; bP0 += 32; bP1 += 32;                               \
    }                                                                           \
    _Pragma("unroll") for (int i = 0; i < 4; ++i)                               \
      _Pragma("unroll") for (int j = 0; j < 4; ++j)                             \
        acc[i][j] = __builtin_amdgcn_mfma_f32_16x16x32_bf16(b_[j], a_[i], acc[i][j], 0, 0, 0); \
  }

// GEMM2b (org): Xb[.,768] x WorgB[768,768] -> out fp32 + bias (written FIRST,
// reduce then accumulates the up-path partials onto it)
__global__ __launch_bounds__(256) void k_gemm2b(const bf16* __restrict__ Xb,
                                                const bf16* __restrict__ WorgB,
                                                float* __restrict__ out,
                                                const float* __restrict__ bias) {
  __shared__ bf16 As[3][128 * 32];
  __shared__ bf16 Bs[3][128 * 32];
  const int wgid = xcd_swizzle(blockIdx.x, 39 * 6);
  const int bmt = wgid / 6;
  const int bnt = wgid % 6;
  const int m0 = bmt * 128, n0 = bnt * 128;
  const int lane = threadIdx.x & 63;
  const int wave = threadIdx.x >> 6;
  const int wm = wave >> 1, wn = wave & 1;
  const int lr = lane & 15, kg = lane >> 4;
  const int slot = (kg ^ ((lr >> 1) & 3)) << 3;
  const int aOff = (wm * 64 + lr) * 32 + slot;
  const int bOff = (wn * 64 + lr) * 32 + slot;

  const int src_slot = (lane & 3) ^ ((lane >> 3) & 3);
  const int srow = (wave * 2) * 16 + (lane >> 2);
  const bf16* aP0 = Xb    + (size_t)(m0 + srow) * D_DIM + (src_slot << 3);
  const bf16* aP1 = aP0 + 16 * D_DIM;
  const bf16* bP0 = WorgB + (size_t)(n0 + srow) * D_DIM + (src_slot << 3);
  const bf16* bP1 = bP0 + 16 * D_DIM;
  const int ldsC0 = (wave * 2) * 512, ldsC1 = ldsC0 + 512;

  f32x4 acc[4][4];
#pragma unroll
  for (int i = 0; i < 4; ++i)
#pragma unroll
    for (int j = 0; j < 4; ++j) acc[i][j] = (f32x4)(0.0f);

  GLDS(aP0, &As[0][ldsC0]); GLDS(aP1, &As[0][ldsC1]);
  GLDS(bP0, &Bs[0][ldsC0]); GLDS(bP1, &Bs[0][ldsC1]);
  aP0 += 32; aP1 += 32; bP0 += 32; bP1 += 32;
  GLDS(aP0, &As[1][ldsC0]); GLDS(aP1, &As[1][ldsC1]);
  GLDS(bP0, &Bs[1][ldsC0]); GLDS(bP1, &Bs[1][ldsC1]);
  aP0 += 32; aP1 += 32; bP0 += 32; bP1 += 32;

  for (int g = 0; g < 7; ++g) {
    G1B_IT(0, true, false)
    G1B_IT(1, true, false)
    G1B_IT(2, true, false)
  }
  G1B_IT(0, true, false)
  G1B_IT(1, false, false)
  G1B_IT(2, false, true)

#pragma unroll
  for (int j = 0; j < 4; ++j) {
    const int cb = n0 + wn * 64 + j * 16 + kg * 4;
    const f32x4 bv = *(const f32x4*)(bias + cb);
#pragma unroll
    for (int i = 0; i < 4; ++i) {
      const int mr = m0 + wm * 64 + i * 16 + lr;
      if (mr < M_TOK) {
        f32x4 o = acc[i][j] + bv;
        *(f32x4*)(out + (size_t)mr * D_DIM + cb) = o;
      }
    }
  }
}

// out += sum of 4 bf16 up-path partials (org + bias already in out)
__global__ __launch_bounds__(256) void k_reduce(const bf16* __restrict__ padd,
                                                float* __restrict__ out) {
  int idx = (blockIdx.x * 256 + threadIdx.x) * 4;
  if (idx >= M_TOK * D_DIM) return;
  float4 s = *(const float4*)(out + idx);
#pragma unroll
  for (int p = 0; p < 4; ++p) {
    union { uint2 u; bf16 h[4]; } v;
    v.u = *(const uint2*)(padd + (size_t)p * M_TOK * D_DIM + idx);
    s.x += (float)v.h[0]; s.y += (float)v.h[1];
    s.z += (float)v.h[2]; s.w += (float)v.h[3];
  }
  *(float4*)(out + idx) = s;
}

// ---------------- launch ----------------

extern "C" void kernel_launch(void* const* d_in, const int* in_sizes, int n_in,
                              void* d_out, int out_size, void* d_ws, size_t ws_size,
                              hipStream_t stream) {
  const float* x     = (const float*)d_in[0];
  const float* W_org = (const float*)d_in[1];
  const float* b_org = (const float*)d_in[2];
  const float* w1    = (const float*)d_in[3];
  const float* b1    = (const float*)d_in[4];
  const float* mid_w = (const float*)d_in[5];
  const float* mid_b = (const float*)d_in[6];
  const float* w_out = (const float*)d_in[7];
  const float* b_out = (const float*)d_in[8];
  float* out = (float*)d_out;

  // workspace carve-up
  bf16* Xb    = (bf16*)d_ws;                        // 5120*768
  bf16* WorgB = Xb + (size_t)M_PAD * D_DIM;         // 768*768
  float* bias    = (float*)(WorgB + (size_t)D_DIM * D_DIM);
  float* partial = bias + 1024;                     // 32*768
  float* diag    = partial + 32 * D_DIM;            // 4096
  u8* Xq   = (u8*)(diag + NR);                      // 5120*768
  u8* W1q  = Xq  + (size_t)M_PAD * D_DIM;           // 4096*768
  u8* W2q  = W1q + (size_t)NR * D_DIM;              // 768*4096
  u8* H2q  = W2q + (size_t)D_DIM * NR;              // 4992*4096
  bf16* padd = (bf16*)(H2q + (size_t)M_GMM * NR);   // 4 * 4928*768

  k_prep_x      <<<(M_PAD * D_DIM / 4) / 256, 256, 0, stream>>>(x, Xb);
  k_prep_xq     <<<(M_PAD * D_DIM / 4) / 256, 256, 0, stream>>>(x, Xq);
  k_prep_w1q    <<<384, 256, 0, stream>>>(w1, W1q);
  k_prep_w2q    <<<64 * 12, 256, 0, stream>>>(w_out, W2q);
  k_prep_worg   <<<(D_DIM * D_DIM / 4 + 255) / 256, 256, 0, stream>>>(W_org, WorgB);
  k_bias_partial<<<32, 256, 0, stream>>>(b_out, partial);
  k_bias_final2 <<<19, 256, 0, stream>>>(partial, b_org, mid_w, bias, diag);

  k_gemm1 <<<39 * 32, 256, 0, stream>>>(Xq, W1q, H2q, b1, diag, mid_b);
  k_gemm2a<<<39 * 6 * 4, 256, 0, stream>>>(H2q, W2q, padd);
  k_gemm2b<<<39 * 6, 256, 0, stream>>>(Xb, WorgB, out, bias);

  k_reduce<<<(M_TOK * D_DIM / 4) / 256, 256, 0, stream>>>(padd, out);
}

// Round 16
// 117.572 us; speedup vs baseline: 1.0290x; 1.0099x over previous
//
#include <hip/hip_runtime.h>
#include <hip/hip_bf16.h>

// Problem constants
#define M_TOK 4928   // B*T = 64*77
#define M_PAD 5120   // Xb/Xq row allocation
#define M_GMM 4992   // 39*128 rows actually computed
#define D_DIM 768
#define NR    4096   // N*R = 1024*4

typedef __bf16 bf16;
typedef unsigned char u8;   // raw fp8 e4m3 byte
typedef __attribute__((ext_vector_type(8))) __bf16 bf16x8;
typedef __attribute__((ext_vector_type(4))) float f32x4;
typedef __attribute__((ext_vector_type(2))) long longx2;
typedef __attribute__((address_space(1))) uint32_t gu32;
typedef __attribute__((address_space(3))) uint32_t su32;

// ALWAYS offset=0 (R11: nonzero offset shifts the LDS destination -> NaN).
#define GLDS(P, LDSP) \
  __builtin_amdgcn_global_load_lds((gu32*)(P), (su32*)(LDSP), 16, 0, 0)

// k-interleave within each 64-byte K-group: storage p = (k&7) + ((k>>5)&1)*8
// + ((k>>3)&3)*16.  Storage-slot kg (16B) holds k {kg*8..+7, 32+kg*8..+7} =
// one lane's BOTH fp8 k-slices -> single conflict-free ds_read_b128
// (R15-verified: SQ_LDS_BANK_CONFLICT = 0).
__device__ __forceinline__ int ilv4(int k) {   // k 4-byte aligned
  return (k & ~63) + (k & 4) + (((k >> 5) & 1) << 3) + (((k >> 3) & 3) << 4);
}
__device__ __forceinline__ int ilv8(int k) {   // k 8-byte aligned
  return (k & ~63) + (((k >> 5) & 1) << 3) + (((k >> 3) & 3) << 4);
}

// pack 4 f32 -> 4 fp8 e4m3 (RNE, saturating) in one u32
__device__ __forceinline__ uint32_t pk_fp8x4(float a, float b, float c, float d) {
  uint32_t w = 0;
  w = (uint32_t)__builtin_amdgcn_cvt_pk_fp8_f32(a, b, (int)w, false);
  w = (uint32_t)__builtin_amdgcn_cvt_pk_fp8_f32(c, d, (int)w, true);
  return w;
}

// sigma-GELU: x * sigmoid(1.702 x); act error swamped by diag(~0.02) squashing.
__device__ __forceinline__ float act_fast(float v) {
  float e = __builtin_amdgcn_exp2f(v * -2.4554677f);
  return v * __builtin_amdgcn_rcpf(1.0f + e);
}

// m204 bijective XCD swizzle
__device__ __forceinline__ int xcd_swizzle(int orig, int nwg) {
  const int q = nwg >> 3, r = nwg & 7;
  const int x = orig & 7, rest = orig >> 3;
  return (x < r ? x * (q + 1) : r * (q + 1) + (x - r) * q) + rest;
}

// ---------------- prep kernels ----------------

// x fp32 -> Xb bf16 AND Xq fp8 (k-interleaved) in one pass; pad rows zero.
__global__ __launch_bounds__(256) void k_prep_x2(const float* __restrict__ x,
                                                 bf16* __restrict__ Xb,
                                                 u8* __restrict__ Xq) {
  int idx = (blockIdx.x * 256 + threadIdx.x) * 4;
  if (idx >= M_PAD * D_DIM) return;
  int m = idx / D_DIM, c = idx % D_DIM;
  union { uint2 u; bf16 h[4]; } o;
  uint32_t w = 0;
  if (m < M_TOK) {
    float4 v = *(const float4*)(x + idx);
    o.h[0] = (bf16)v.x; o.h[1] = (bf16)v.y; o.h[2] = (bf16)v.z; o.h[3] = (bf16)v.w;
    w = pk_fp8x4(v.x, v.y, v.z, v.w);
  } else {
    o.h[0] = o.h[1] = o.h[2] = o.h[3] = (bf16)0.0f;
  }
  *(uint2*)(Xb + idx) = o.u;
  *(uint32_t*)(Xq + (size_t)m * D_DIM + ilv4(c)) = w;
}

// w1 fp32 [N][D][R] -> W1q fp8 [4096 j][768 d] (k-interleaved), scaled x64.
__global__ __launch_bounds__(256) void k_prep_w1q(const float* __restrict__ w1,
                                                  u8* __restrict__ W1q) {
  int gid = blockIdx.x * 256 + threadIdx.x;   // 98304
  int n = gid / 96, oct = gid % 96;
  const float4* src = (const float4*)w1 + (size_t)n * D_DIM + oct * 8;
  float e[4][8];
#pragma unroll
  for (int d = 0; d < 8; ++d) {
    float4 v = src[d];
    e[0][d] = v.x * 64.0f; e[1][d] = v.y * 64.0f;
    e[2][d] = v.z * 64.0f; e[3][d] = v.w * 64.0f;
  }
  const int cofs = ilv8(oct * 8);
#pragma unroll
  for (int r = 0; r < 4; ++r) {
    uint2 o;
    o.x = pk_fp8x4(e[r][0], e[r][1], e[r][2], e[r][3]);
    o.y = pk_fp8x4(e[r][4], e[r][5], e[r][6], e[r][7]);
    *(uint2*)(W1q + (size_t)(n * 4 + r) * D_DIM + cofs) = o;
  }
}

// w_out fp32 [4096 k][768 d] -> W2q fp8 [768 d][4096 k] = 16*w_out, interleaved
__global__ __launch_bounds__(256) void k_prep_w2q(const float* __restrict__ w_out,
                                                  u8* __restrict__ W2q) {
  __shared__ float S[64 * 65];
  const int bk = blockIdx.x & 63, bd = blockIdx.x >> 6;  // 64 k-tiles x 12 d-tiles
  const int k0 = bk * 64, d0 = bd * 64;
  const int tr = threadIdx.x >> 4;        // 0..15
  const int tc = (threadIdx.x & 15) * 4;  // 0..60
#pragma unroll
  for (int p = 0; p < 4; ++p) {
    const int kr = tr + p * 16;
    float4 v = *(const float4*)(w_out + (size_t)(k0 + kr) * D_DIM + d0 + tc);
    S[kr * 65 + tc + 0] = v.x; S[kr * 65 + tc + 1] = v.y;
    S[kr * 65 + tc + 2] = v.z; S[kr * 65 + tc + 3] = v.w;
  }
  __syncthreads();
#pragma unroll
  for (int p = 0; p < 4; ++p) {
    const int dr = tr + p * 16;
    uint32_t w = pk_fp8x4(16.0f * S[(tc + 0) * 65 + dr], 16.0f * S[(tc + 1) * 65 + dr],
                          16.0f * S[(tc + 2) * 65 + dr], 16.0f * S[(tc + 3) * 65 + dr]);
    *(uint32_t*)(W2q + (size_t)(d0 + dr) * NR + k0 + ilv4(tc)) = w;
  }
}

// W_org fp32 [768][768] -> bf16 row-major copy
__global__ __launch_bounds__(256) void k_prep_worg(const float* __restrict__ W_org,
                                                   bf16* __restrict__ WorgB) {
  int idx = (blockIdx.x * 256 + threadIdx.x) * 4;
  if (idx >= D_DIM * D_DIM) return;
  float4 v = *(const float4*)(W_org + idx);
  union { uint2 u; bf16 h[4]; } o;
  o.h[0] = (bf16)v.x; o.h[1] = (bf16)v.y; o.h[2] = (bf16)v.z; o.h[3] = (bf16)v.w;
  *(uint2*)(WorgB + idx) = o.u;
}

__global__ __launch_bounds__(256) void k_bias_partial(const float* __restrict__ b_out,
                                                      float* __restrict__ partial) {
  int b = blockIdx.x;
  for (int d = threadIdx.x; d < D_DIM; d += 256) {
    float s = 0.0f;
    for (int n = b * 32; n < b * 32 + 32; ++n) s += b_out[n * D_DIM + d];
    partial[b * D_DIM + d] = s;
  }
}

// blocks 0-2: bias_total; blocks 3-18: diag[j] = mid_w[n][r][r]
__global__ __launch_bounds__(256) void k_bias_final2(const float* __restrict__ partial,
                                                     const float* __restrict__ b_org,
                                                     const float* __restrict__ mid_w,
                                                     float* __restrict__ bias_total,
                                                     float* __restrict__ diag) {
  int b = blockIdx.x;
  if (b < 3) {
    int d = b * 256 + threadIdx.x;
    if (d >= D_DIM) return;
    float s = 0.0f;
#pragma unroll
    for (int p = 0; p < 32; ++p) s += partial[p * D_DIM + d];
    bias_total[d] = b_org[d] + 0.25f * s;
  } else {
    int j = (b - 3) * 256 + threadIdx.x;
    diag[j] = mid_w[(j >> 2) * 16 + (j & 3) * 5];
  }
}

// ---------------- fp8 128x128/BK64 engine (R15-verified, conflicts=0) -------
// 3 LDS slots of 128x64B; per iter: vmcnt(4) -> barrier -> 8x ds_read_b128 ->
// stage tile kt+2 (4 GLDS, pointers += 64) -> 32 MFMA (swapped operands).

#define G1F_IT(S_, DO_STG, LAST_)                                               \
  {                                                                             \
    if (LAST_) { asm volatile("s_waitcnt vmcnt(0)" ::: "memory"); }             \
    else       { asm volatile("s_waitcnt vmcnt(4)" ::: "memory"); }             \
    asm volatile("s_barrier" ::: "memory");                                     \
    longx2 av[4], bv[4];                                                        \
    _Pragma("unroll") for (int i = 0; i < 4; ++i)                               \
      av[i] = *(const longx2*)(&As[S_][aOff + i * 1024]);                       \
    _Pragma("unroll") for (int j = 0; j < 4; ++j)                               \
      bv[j] = *(const longx2*)(&Bs[S_][bOff + j * 1024]);                       \
    if (DO_STG) {                                                               \
      GLDS(aP0, &As[((S_) + 2) % 3][ldsC0]);                                    \
      GLDS(aP1, &As[((S_) + 2) % 3][ldsC1]);                                    \
      GLDS(bP0, &Bs[((S_) + 2) % 3][ldsC0]);                                    \
      GLDS(bP1, &Bs[((S_) + 2) % 3][ldsC1]);                                    \
      aP0 += 64; aP1 += 64; bP0 += 64; bP1 += 64;                               \
    }                                                                           \
    _Pragma("unroll") for (int i = 0; i < 4; ++i)                               \
      _Pragma("unroll") for (int j = 0; j < 4; ++j)                             \
        acc[i][j] = __builtin_amdgcn_mfma_f32_16x16x32_fp8_fp8(bv[j][0], av[i][0], acc[i][j], 0, 0, 0); \
    _Pragma("unroll") for (int i = 0; i < 4; ++i)                               \
      _Pragma("unroll") for (int j = 0; j < 4; ++j)                             \
        acc[i][j] = __builtin_amdgcn_mfma_f32_16x16x32_fp8_fp8(bv[j][1], av[i][1], acc[i][j], 0, 0, 0); \
  }

// GEMM1: Xq[.,768]8 x W1q[4096,768]8 -> H2q fp8 [4992,4096] (x128, interleaved)
__global__ __launch_bounds__(256) void k_gemm1(const u8* __restrict__ Xq,
                                               const u8* __restrict__ W1q,
                                               u8* __restrict__ H2q,
                                               const float* __restrict__ b1,
                                               const float* __restrict__ diag,
                                               const float* __restrict__ midb) {
  __shared__ u8 As[3][128 * 64];
  __shared__ u8 Bs[3][128 * 64];
  const int wgid = xcd_swizzle(blockIdx.x, 39 * 32);
  const int bmt = wgid >> 5;
  const int bnt = wgid & 31;
  const int m0 = bmt * 128, n0 = bnt * 128;
  const int lane = threadIdx.x & 63;
  const int wave = threadIdx.x >> 6;
  const int wm = wave >> 1, wn = wave & 1;
  const int lr = lane & 15, kg = lane >> 4;
  const int slotB = (kg ^ ((lr >> 1) & 3)) << 4;
  const int aOff = (wm * 64 + lr) * 64 + slotB;
  const int bOff = (wn * 64 + lr) * 64 + slotB;

  const int src_slot = (lane & 3) ^ ((lane >> 3) & 3);
  const int srow = (wave * 2) * 16 + (lane >> 2);
  const u8* aP0 = Xq  + (size_t)(m0 + srow) * D_DIM + (src_slot << 4);
  const u8* aP1 = aP0 + 16 * D_DIM;
  const u8* bP0 = W1q + (size_t)(n0 + srow) * D_DIM + (src_slot << 4);
  const u8* bP1 = bP0 + 16 * D_DIM;
  const int ldsC0 = (wave * 2) * 1024, ldsC1 = ldsC0 + 1024;

  f32x4 acc[4][4];
#pragma unroll
  for (int i = 0; i < 4; ++i)
#pragma unroll
    for (int j = 0; j < 4; ++j) acc[i][j] = (f32x4)(0.0f);

  GLDS(aP0, &As[0][ldsC0]); GLDS(aP1, &As[0][ldsC1]);
  GLDS(bP0, &Bs[0][ldsC0]); GLDS(bP1, &Bs[0][ldsC1]);
  aP0 += 64; aP1 += 64; bP0 += 64; bP1 += 64;
  GLDS(aP0, &As[1][ldsC0]); GLDS(aP1, &As[1][ldsC1]);
  GLDS(bP0, &Bs[1][ldsC0]); GLDS(bP1, &Bs[1][ldsC1]);
  aP0 += 64; aP1 += 64; bP0 += 64; bP1 += 64;

  for (int g = 0; g < 3; ++g) {
    G1F_IT(0, true, false)
    G1F_IT(1, true, false)
    G1F_IT(2, true, false)
  }
  G1F_IT(0, true, false)
  G1F_IT(1, false, false)
  G1F_IT(2, false, true)

  // epilogue: acc = 64*h1 -> x2^-6; h2 stored fp8 x128, k-interleaved position
#pragma unroll
  for (int j = 0; j < 4; ++j) {
    const int jcb = n0 + wn * 64 + j * 16 + kg * 4;
    const float4 b1v = *(const float4*)(b1 + jcb);
    const float4 dgv = *(const float4*)(diag + jcb);
    const float4 mbv = *(const float4*)(midb + jcb);
    const int jq = j * 16 + kg * 4;
    const int pl = (jq & 4) + (((jq >> 5) & 1) << 3) + (((jq >> 3) & 3) << 4);
#pragma unroll
    for (int i = 0; i < 4; ++i) {
      const int mr = m0 + wm * 64 + i * 16 + lr;
      float h, f0, f1, f2, f3;
      h = act_fast(fmaf(acc[i][j][0], 0.015625f, b1v.x)); f0 = act_fast(h * dgv.x + mbv.x);
      h = act_fast(fmaf(acc[i][j][1], 0.015625f, b1v.y)); f1 = act_fast(h * dgv.y + mbv.y);
      h = act_fast(fmaf(acc[i][j][2], 0.015625f, b1v.z)); f2 = act_fast(h * dgv.z + mbv.z);
      h = act_fast(fmaf(acc[i][j][3], 0.015625f, b1v.w)); f3 = act_fast(h * dgv.w + mbv.w);
      uint32_t w = pk_fp8x4(f0 * 128.0f, f1 * 128.0f, f2 * 128.0f, f3 * 128.0f);
      *(uint32_t*)(H2q + (size_t)mr * NR + (n0 + wn * 64) + pl) = w;
    }
  }
}

// GEMM2a (up-path): H2q[4992,4096]8 x W2q[768,4096]8 -> bf16 partials[4].
__global__ __launch_bounds__(256) void k_gemm2a(const u8* __restrict__ H2q,
                                                const u8* __restrict__ W2q,
                                                bf16* __restrict__ padd) {
  __shared__ u8 As[3][128 * 64];
  __shared__ u8 Bs[3][128 * 64];
  const int wgid = xcd_swizzle(blockIdx.x, 39 * 6 * 4);
  const int bmt = wgid / 24;
  const int rem = wgid % 24;
  const int ks  = rem / 6;
  const int bnt = rem % 6;               // 6 consecutive share A-panel
  const int m0 = bmt * 128, n0 = bnt * 128;
  const int kbase = ks * 1024;           // K bytes (64-aligned: interleave intact)
  const int lane = threadIdx.x & 63;
  const int wave = threadIdx.x >> 6;
  const int wm = wave >> 1, wn = wave & 1;
  const int lr = lane & 15, kg = lane >> 4;
  const int slotB = (kg ^ ((lr >> 1) & 3)) << 4;
  const int aOff = (wm * 64 + lr) * 64 + slotB;
  const int bOff = (wn * 64 + lr) * 64 + slotB;

  const int src_slot = (lane & 3) ^ ((lane >> 3) & 3);
  const int srow = (wave * 2) * 16 + (lane >> 2);
  const u8* aP0 = H2q + (size_t)(m0 + srow) * NR + kbase + (src_slot << 4);
  const u8* aP1 = aP0 + 16 * NR;
  const u8* bP0 = W2q + (size_t)(n0 + srow) * NR + kbase + (src_slot << 4);
  const u8* bP1 = bP0 + 16 * NR;
  const int ldsC0 = (wave * 2) * 1024, ldsC1 = ldsC0 + 1024;

  f32x4 acc[4][4];
#pragma unroll
  for (int i = 0; i < 4; ++i)
#pragma unroll
    for (int j = 0; j < 4; ++j) acc[i][j] = (f32x4)(0.0f);

  GLDS(aP0, &As[0][ldsC0]); GLDS(aP1, &As[0][ldsC1]);
  GLDS(bP0, &Bs[0][ldsC0]); GLDS(bP1, &Bs[0][ldsC1]);
  aP0 += 64; aP1 += 64; bP0 += 64; bP1 += 64;
  GLDS(aP0, &As[1][ldsC0]); GLDS(aP1, &As[1][ldsC1]);
  GLDS(bP0, &Bs[1][ldsC0]); GLDS(bP1, &Bs[1][ldsC1]);
  aP0 += 64; aP1 += 64; bP0 += 64; bP1 += 64;

  // 16 iters: kt0-11 (4 groups), kt12-13 stage tail, kt14-15 drain
  for (int g = 0; g < 4; ++g) {
    G1F_IT(0, true, false)
    G1F_IT(1, true, false)
    G1F_IT(2, true, false)
  }
  G1F_IT(0, true, false)   // kt12 stages t14
  G1F_IT(1, true, false)   // kt13 stages t15
  G1F_IT(2, false, false)  // kt14
  G1F_IT(0, false, true)   // kt15

  bf16* dst = padd + (size_t)ks * M_TOK * D_DIM;
#pragma unroll
  for (int j = 0; j < 4; ++j) {
    const int cb = n0 + wn * 64 + j * 16 + kg * 4;
#pragma unroll
    for (int i = 0; i < 4; ++i) {
      const int mr = m0 + wm * 64 + i * 16 + lr;
      if (mr < M_TOK) {
        union { uint2 u; bf16 h[4]; } o;
        o.h[0] = (bf16)(acc[i][j][0] * 4.8828125e-4f);
        o.h[1] = (bf16)(acc[i][j][1] * 4.8828125e-4f);
        o.h[2] = (bf16)(acc[i][j][2] * 4.8828125e-4f);
        o.h[3] = (bf16)(acc[i][j][3] * 4.8828125e-4f);
        *(uint2*)(dst + (size_t)mr * D_DIM + cb) = o.u;
      }
    }
  }
}

// ---------------- bf16 128x128/BK32 engine (R12-verified) for org path ------

#define G1B_IT(S_, DO_STG, LAST_)                                               \
  {                                                                             \
    if (LAST_) { asm volatile("s_waitcnt vmcnt(0)" ::: "memory"); }             \
    else       { asm volatile("s_waitcnt vmcnt(4)" ::: "memory"); }             \
    asm volatile("s_barrier" ::: "memory");                                     \
    bf16x8 a_[4], b_[4];                                                        \
    _Pragma("unroll") for (int i = 0; i < 4; ++i)                               \
      a_[i] = *(const bf16x8*)(&As[S_][aOff + i * 512]);                        \
    _Pragma("unroll") for (int j = 0; j < 4; ++j)                               \
      b_[j] = *(const bf16x8*)(&Bs[S_][bOff + j * 512]);                        \
    if (DO_STG) {                                                               \
      GLDS(aP0, &As[((S_) + 2) % 3][ldsC0]);                                    \
      GLDS(aP1, &As[((S_) + 2) % 3][ldsC1]);                                    \
      GLDS(bP0, &Bs[((S_) + 2) % 3][ldsC0]);                                    \
      GLDS(bP1, &Bs[((S_) + 2) % 3][ldsC1]);                                    \
      aP0 += 32; aP1 += 32; bP0 += 32; bP1 += 32;                               \
    }                                                                           \
    _Pragma("unroll") for (int i = 0; i < 4; ++i)                               \
      _Pragma("unroll") for (int j = 0; j < 4; ++j)                             \
        acc[i][j] = __builtin_amdgcn_mfma_f32_16x16x32_bf16(b_[j], a_[i], acc[i][j], 0, 0, 0); \
  }

// GEMM2b (org): Xb x WorgB -> out = acc + bias + sum of 4 up-path partials
// (fused reduce: runs AFTER gemm2a, reads padd in the epilogue)
__global__ __launch_bounds__(256) void k_gemm2b(const bf16* __restrict__ Xb,
                                                const bf16* __restrict__ WorgB,
                                                const bf16* __restrict__ padd,
                                                float* __restrict__ out,
                                                const float* __restrict__ bias) {
  __shared__ bf16 As[3][128 * 32];
  __shared__ bf16 Bs[3][128 * 32];
  const int wgid = xcd_swizzle(blockIdx.x, 39 * 6);
  const int bmt = wgid / 6;
  const int bnt = wgid % 6;
  const int m0 = bmt * 128, n0 = bnt * 128;
  const int lane = threadIdx.x & 63;
  const int wave = threadIdx.x >> 6;
  const int wm = wave >> 1, wn = wave & 1;
  const int lr = lane & 15, kg = lane >> 4;
  const int slot = (kg ^ ((lr >> 1) & 3)) << 3;
  const int aOff = (wm * 64 + lr) * 32 + slot;
  const int bOff = (wn * 64 + lr) * 32 + slot;

  const int src_slot = (lane & 3) ^ ((lane >> 3) & 3);
  const int srow = (wave * 2) * 16 + (lane >> 2);
  const bf16* aP0 = Xb    + (size_t)(m0 + srow) * D_DIM + (src_slot << 3);
  const bf16* aP1 = aP0 + 16 * D_DIM;
  const bf16* bP0 = WorgB + (size_t)(n0 + srow) * D_DIM + (src_slot << 3);
  const bf16* bP1 = bP0 + 16 * D_DIM;
  const int ldsC0 = (wave * 2) * 512, ldsC1 = ldsC0 + 512;

  f32x4 acc[4][4];
#pragma unroll
  for (int i = 0; i < 4; ++i)
#pragma unroll
    for (int j = 0; j < 4; ++j) acc[i][j] = (f32x4)(0.0f);

  GLDS(aP0, &As[0][ldsC0]); GLDS(aP1, &As[0][ldsC1]);
  GLDS(bP0, &Bs[0][ldsC0]); GLDS(bP1, &Bs[0][ldsC1]);
  aP0 += 32; aP1 += 32; bP0 += 32; bP1 += 32;
  GLDS(aP0, &As[1][ldsC0]); GLDS(aP1, &As[1][ldsC1]);
  GLDS(bP0, &Bs[1][ldsC0]); GLDS(bP1, &Bs[1][ldsC1]);
  aP0 += 32; aP1 += 32; bP0 += 32; bP1 += 32;

  for (int g = 0; g < 7; ++g) {
    G1B_IT(0, true, false)
    G1B_IT(1, true, false)
    G1B_IT(2, true, false)
  }
  G1B_IT(0, true, false)
  G1B_IT(1, false, false)
  G1B_IT(2, false, true)

  // fused epilogue: out = acc + bias + sum_p padd[p]
#pragma unroll
  for (int j = 0; j < 4; ++j) {
    const int cb = n0 + wn * 64 + j * 16 + kg * 4;
    const f32x4 bv = *(const f32x4*)(bias + cb);
#pragma unroll
    for (int i = 0; i < 4; ++i) {
      const int mr = m0 + wm * 64 + i * 16 + lr;
      if (mr < M_TOK) {
        const size_t base = (size_t)mr * D_DIM + cb;
        f32x4 o = acc[i][j] + bv;
#pragma unroll
        for (int p = 0; p < 4; ++p) {
          union { uint2 u; bf16 h[4]; } v;
          v.u = *(const uint2*)(padd + (size_t)p * M_TOK * D_DIM + base);
          o[0] += (float)v.h[0]; o[1] += (float)v.h[1];
          o[2] += (float)v.h[2]; o[3] += (float)v.h[3];
        }
        *(f32x4*)(out + base) = o;
      }
    }
  }
}

// ---------------- launch ----------------

extern "C" void kernel_launch(void* const* d_in, const int* in_sizes, int n_in,
                              void* d_out, int out_size, void* d_ws, size_t ws_size,
                              hipStream_t stream) {
  const float* x     = (const float*)d_in[0];
  const float* W_org = (const float*)d_in[1];
  const float* b_org = (const float*)d_in[2];
  const float* w1    = (const float*)d_in[3];
  const float* b1    = (const float*)d_in[4];
  const float* mid_w = (const float*)d_in[5];
  const float* mid_b = (const float*)d_in[6];
  const float* w_out = (const float*)d_in[7];
  const float* b_out = (const float*)d_in[8];
  float* out = (float*)d_out;

  // workspace carve-up
  bf16* Xb    = (bf16*)d_ws;                        // 5120*768
  bf16* WorgB = Xb + (size_t)M_PAD * D_DIM;         // 768*768
  float* bias    = (float*)(WorgB + (size_t)D_DIM * D_DIM);
  float* partial = bias + 1024;                     // 32*768
  float* diag    = partial + 32 * D_DIM;            // 4096
  u8* Xq   = (u8*)(diag + NR);                      // 5120*768
  u8* W1q  = Xq  + (size_t)M_PAD * D_DIM;           // 4096*768
  u8* W2q  = W1q + (size_t)NR * D_DIM;              // 768*4096
  u8* H2q  = W2q + (size_t)D_DIM * NR;              // 4992*4096
  bf16* padd = (bf16*)(H2q + (size_t)M_GMM * NR);   // 4 * 4928*768

  k_prep_x2     <<<(M_PAD * D_DIM / 4) / 256, 256, 0, stream>>>(x, Xb, Xq);
  k_prep_w1q    <<<384, 256, 0, stream>>>(w1, W1q);
  k_prep_w2q    <<<64 * 12, 256, 0, stream>>>(w_out, W2q);
  k_prep_worg   <<<(D_DIM * D_DIM / 4 + 255) / 256, 256, 0, stream>>>(W_org, WorgB);
  k_bias_partial<<<32, 256, 0, stream>>>(b_out, partial);
  k_bias_final2 <<<19, 256, 0, stream>>>(partial, b_org, mid_w, bias, diag);

  k_gemm1 <<<39 * 32, 256, 0, stream>>>(Xq, W1q, H2q, b1, diag, mid_b);
  k_gemm2a<<<39 * 6 * 4, 256, 0, stream>>>(H2q, W2q, padd);
  k_gemm2b<<<39 * 6, 256, 0, stream>>>(Xb, WorgB, padd, out, bias);
}